// Round 1
// baseline (416.514 us; speedup 1.0000x reference)
//
#include <hip/hip_runtime.h>
#include <stdint.h>

#define NPOLAR 1024
#define KT 512
#define KP 523
#define BLOCK 256
#define PITCH 33   // 32 words + 1 pad -> bank-conflict-free for both access patterns

__global__ __launch_bounds__(BLOCK) void polar_enc_kernel(
    const float* __restrict__ u,
    const float* __restrict__ crc_gen,
    const int* __restrict__ info_pos,
    const int* __restrict__ perm_out,
    float* __restrict__ out)
{
    __shared__ uint32_t xl[BLOCK * PITCH];   // packed post-butterfly rows
    __shared__ uint32_t gc[11 * 16];         // packed CRC generator columns

    const int t   = threadIdx.x;
    const int blk = blockIdx.x;
    const int row = blk * BLOCK + t;

    // ---- build packed CRC columns (176 words) ----
    if (t < 176) {
        int j = t / 16, w = t % 16;
        uint32_t g = 0;
        #pragma unroll
        for (int i = 0; i < 32; ++i) {
            float f = crc_gen[(32 * w + i) * 11 + j];
            g |= ((__float_as_uint(f) >> 29) & 1u) << i;
        }
        gc[j * 16 + w] = g;
    }

    // ---- Phase A: pack this thread's row (512 floats -> 16 words) ----
    uint32_t uw[16];
    const float4* uv = reinterpret_cast<const float4*>(u + (size_t)row * KT);
    #pragma unroll
    for (int w = 0; w < 16; ++w) {
        uint32_t acc = 0;
        #pragma unroll
        for (int q = 0; q < 8; ++q) {
            float4 f = uv[w * 8 + q];
            acc |= ((__float_as_uint(f.x) >> 29) & 1u) << (4 * q + 0);
            acc |= ((__float_as_uint(f.y) >> 29) & 1u) << (4 * q + 1);
            acc |= ((__float_as_uint(f.z) >> 29) & 1u) << (4 * q + 2);
            acc |= ((__float_as_uint(f.w) >> 29) & 1u) << (4 * q + 3);
        }
        uw[w] = acc;
    }

    __syncthreads();   // gc ready

    // ---- Phase B: CRC-11 parity (11 bits) ----
    uint32_t parity = 0;
    #pragma unroll
    for (int j = 0; j < 11; ++j) {
        uint32_t acc = 0;
        #pragma unroll
        for (int w = 0; w < 16; ++w) acc ^= uw[w] & gc[j * 16 + w];
        parity |= (uint32_t)(__popc(acc) & 1) << j;
    }

    // ---- Phase C: scatter 523 bits into the 1024-position frame (LDS) ----
    #pragma unroll
    for (int w = 0; w < 32; ++w) xl[t * PITCH + w] = 0;
    {
        int cw = -1; uint32_t cur = 0;
        #pragma unroll
        for (int sw = 0; sw < 17; ++sw) {
            uint32_t src = (sw < 16) ? uw[sw] : parity;
            const int nb = (sw < 16) ? 32 : 11;
            for (int b = 0; b < nb; ++b) {
                int pos = info_pos[sw * 32 + b];   // sorted ascending, uniform
                int w = pos >> 5;
                if (w != cw) {
                    if (cw >= 0) xl[t * PITCH + cw] = cur;
                    cur = 0; cw = w;
                }
                cur |= ((src >> b) & 1u) << (pos & 31);
            }
        }
        xl[t * PITCH + cw] = cur;   // final flush (always >=1 bit seen)
    }

    // ---- Phase D: 10-stage polar butterfly, fully in registers ----
    uint32_t x[32];
    #pragma unroll
    for (int w = 0; w < 32; ++w) x[w] = xl[t * PITCH + w];
    #pragma unroll
    for (int w = 0; w < 32; ++w) {
        uint32_t v = x[w];
        v ^= (v >> 1)  & 0x55555555u;
        v ^= (v >> 2)  & 0x33333333u;
        v ^= (v >> 4)  & 0x0F0F0F0Fu;
        v ^= (v >> 8)  & 0x00FF00FFu;
        v ^= (v >> 16) & 0x0000FFFFu;
        x[w] = v;
    }
    #pragma unroll
    for (int d = 1; d <= 16; d <<= 1) {
        #pragma unroll
        for (int w = 0; w < 32; ++w)
            if ((w & d) == 0) x[w] ^= x[w + d];
    }
    #pragma unroll
    for (int w = 0; w < 32; ++w) xl[t * PITCH + w] = x[w];

    __syncthreads();   // all rows of this block finalized in LDS

    // ---- Phase E: permuted expansion, block-cooperative, coalesced stores ----
    // Thread t owns output columns 4t..4t+3 for every row of the block.
    const int4 pv = reinterpret_cast<const int4*>(perm_out)[t];
    const int a0 = pv.x >> 5, s0 = pv.x & 31;
    const int a1 = pv.y >> 5, s1 = pv.y & 31;
    const int a2 = pv.z >> 5, s2 = pv.z & 31;
    const int a3 = pv.w >> 5, s3 = pv.w & 31;

    float4* outv = reinterpret_cast<float4*>(out) + (size_t)blk * BLOCK * (NPOLAR / 4) + t;
    #pragma unroll 4
    for (int k = 0; k < BLOCK; ++k) {
        const uint32_t* rowp = &xl[k * PITCH];
        float4 o;
        o.x = (float)((rowp[a0] >> s0) & 1u);
        o.y = (float)((rowp[a1] >> s1) & 1u);
        o.z = (float)((rowp[a2] >> s2) & 1u);
        o.w = (float)((rowp[a3] >> s3) & 1u);
        outv[(size_t)k * (NPOLAR / 4)] = o;
    }
}

extern "C" void kernel_launch(void* const* d_in, const int* in_sizes, int n_in,
                              void* d_out, int out_size, void* d_ws, size_t ws_size,
                              hipStream_t stream) {
    const float* u        = (const float*)d_in[0];
    const float* crc_gen  = (const float*)d_in[1];
    const int*   info_pos = (const int*)d_in[2];
    // d_in[3] = ind_gather (structure derived analytically; unused)
    const int*   perm_out = (const int*)d_in[4];
    float* out = (float*)d_out;

    const int rows = in_sizes[0] / KT;           // 65536
    const int grid = rows / BLOCK;               // 256 blocks

    polar_enc_kernel<<<grid, BLOCK, 0, stream>>>(u, crc_gen, info_pos, perm_out, out);
}